// Round 12
// baseline (276.706 us; speedup 1.0000x reference)
//
#include <hip/hip_runtime.h>
#include <hip/hip_bf16.h>
#include <math.h>

typedef __bf16 bf16;
typedef __bf16 bf16x2 __attribute__((ext_vector_type(2)));
typedef __bf16 bf16x4 __attribute__((ext_vector_type(4)));
typedef __bf16 bf16x8 __attribute__((ext_vector_type(8)));
typedef float  f32x4  __attribute__((ext_vector_type(4)));

#define NB 4
#define SS 8192
#define DD 1024
#define MM 32768
#define KK 1024
#define NN 1024
#define PI_F 3.14159265358979323846f

__device__ __forceinline__ void gl2lds16(const bf16* g, bf16* l) {
    __builtin_amdgcn_global_load_lds(
        (const __attribute__((address_space(1))) void*)g,
        (__attribute__((address_space(3))) void*)l, 16, 0, 0);
}

// ---- W build + hm zero (x-cast now fused into GEMM1) ----
__global__ __launch_bounds__(256) void prep_w(const float* __restrict__ W_proj,
                                              const float* __restrict__ freqs,
                                              const float* __restrict__ W_out,
                                              bf16* __restrict__ WbT1,
                                              bf16* __restrict__ WoT,
                                              float* __restrict__ hm) {
    int idx = blockIdx.x * 256 + threadIdx.x;   // n*1024 + k
    int n = idx >> 10, k = idx & 1023;
    int h = n >> 7, d = n & 127;
    float c = cosf(PI_F * freqs[n]);
    WbT1[idx] = (bf16)(W_proj[(size_t)h * (DD * 128) + (size_t)k * 128 + d] * c);
    WoT[idx]  = (bf16)(W_out[(size_t)k * DD + n]);
    if (idx < NB * DD) hm[idx] = 0.0f;
}

// ============ shared GEMM plumbing (256x256x64, 8 waves, 128KB LDS) ============
#define FENCE  asm volatile("" ::: "memory")
#define BARRIER do { FENCE; __builtin_amdgcn_s_barrier(); FENCE; } while (0)
#define PRIO1  __builtin_amdgcn_s_setprio(1)
#define PRIO0  __builtin_amdgcn_s_setprio(0)
#define VMC(N) asm volatile("s_waitcnt vmcnt(" #N ")" ::: "memory")
#define LGKM0  asm volatile("s_waitcnt lgkmcnt(0)" ::: "memory")
#define NOPS   ((void)0)

#define STG(g0, g1, uk, ldsBase)                                  \
    gl2lds16((g0) + (uk), &sm[(ldsBase) + w * 512]);              \
    gl2lds16((g1) + (uk), &sm[(ldsBase) + 4096 + w * 512]);

#define READ_A2(MQ, ab)                                                          \
    _Pragma("unroll") for (int m_ = 0; m_ < 4; ++m_) {                           \
        a[m_ * 2 + 0] = *(const bf16x8*)&sm[(ab) + aoff0 + ((MQ)*64 + m_*16)*64];\
        a[m_ * 2 + 1] = *(const bf16x8*)&sm[(ab) + aoff1 + ((MQ)*64 + m_*16)*64];\
    }
#define READ_B2(NQ, bfr, bb)                                                     \
    _Pragma("unroll") for (int n_ = 0; n_ < 2; ++n_) {                           \
        bfr[n_ * 2 + 0] = *(const bf16x8*)&sm[(bb) + boff0 + ((NQ)*32 + n_*16)*64];\
        bfr[n_ * 2 + 1] = *(const bf16x8*)&sm[(bb) + boff1 + ((NQ)*32 + n_*16)*64];\
    }

#define MFMA_Q(MQ, NQ, bfr)                                                    \
    _Pragma("unroll") for (int m_ = 0; m_ < 4; ++m_)                           \
    _Pragma("unroll") for (int n_ = 0; n_ < 2; ++n_)                           \
    _Pragma("unroll") for (int ks_ = 0; ks_ < 2; ++ks_)                        \
        acc[(MQ) * 4 + m_][(NQ) * 2 + n_] =                                    \
            __builtin_amdgcn_mfma_f32_16x16x32_bf16(                           \
                a[m_ * 2 + ks_], bfr[n_ * 2 + ks_],                            \
                acc[(MQ) * 4 + m_][(NQ) * 2 + n_], 0, 0, 0);

// ---------------- GEMM1: A = x fp32, reg-staged with swizzle-ADDR ds_writes ----------------
// A-issue: 8 float4 from LOGICAL addresses (no source swizzle).
#define ISSA(uk)                                                               \
    areg[0] = *(const f32x4*)(gAh0 + (uk));                                    \
    areg[1] = *(const f32x4*)(gAh0 + (uk) + 4);                                \
    areg[2] = *(const f32x4*)(gAh0 + (uk) + 8);                                \
    areg[3] = *(const f32x4*)(gAh0 + (uk) + 12);                               \
    areg[4] = *(const f32x4*)(gAh1 + (uk));                                    \
    areg[5] = *(const f32x4*)(gAh1 + (uk) + 4);                                \
    areg[6] = *(const f32x4*)(gAh1 + (uk) + 8);                                \
    areg[7] = *(const f32x4*)(gAh1 + (uk) + 12);

#define CVT1(dst, lo, hi)                                                      \
    { bf16x8 w_; w_[0]=(bf16)(lo).x; w_[1]=(bf16)(lo).y; w_[2]=(bf16)(lo).z;   \
      w_[3]=(bf16)(lo).w; w_[4]=(bf16)(hi).x; w_[5]=(bf16)(hi).y;              \
      w_[6]=(bf16)(hi).z; w_[7]=(bf16)(hi).w; *(bf16x8*)(dst) = w_; }

// writes to swizzled phys chunks (conflict-free: lanes cover all 8 chunk groups)
#define WRA(ab)                                                                \
    CVT1(&sm[(ab) + wA0],        areg[0], areg[1]);                            \
    CVT1(&sm[(ab) + wA1],        areg[2], areg[3]);                            \
    CVT1(&sm[(ab) + 8192 + wA0], areg[4], areg[5]);                            \
    CVT1(&sm[(ab) + 8192 + wA1], areg[6], areg[7]);

// R8 backbone; A(t+1): issue@p1, write@p4 (after VM4); A(t+2): issue@p5, write@p8.
// FIFO at p4: [B(t+1)4, A(t+1)8, B(t+2)4] -> VMC(4) retires B(t+1)+A(t+1). Same @p8.
#define ITER_G1(uk1, STG3, STG4, STG7, STG8, ISS5, VM4, VM8, WR8)              \
  { BARRIER; ISSA(uk1);                                                        \
    PRIO1; READ_A2(0, 0); READ_B2(0, blo, 32768); MFMA_Q(0, 0, blo); PRIO0;    \
    BARRIER;                                                                   \
    PRIO1; READ_B2(1, bhi, 32768); MFMA_Q(0, 1, bhi); PRIO0;                   \
    BARRIER; STG3;                                                             \
    PRIO1; READ_A2(1, 0); MFMA_Q(1, 1, bhi); PRIO0;                            \
    BARRIER; STG4; VM4; WRA(16384);                                            \
    PRIO1; MFMA_Q(1, 0, blo); PRIO0; LGKM0;                                    \
    BARRIER; ISS5;                                                             \
    PRIO1; READ_A2(0, 16384); READ_B2(0, blo, 49152); MFMA_Q(0, 0, blo); PRIO0;\
    BARRIER;                                                                   \
    PRIO1; READ_B2(1, bhi, 49152); MFMA_Q(0, 1, bhi); PRIO0;                   \
    BARRIER; STG7;                                                             \
    PRIO1; READ_A2(1, 16384); MFMA_Q(1, 1, bhi); PRIO0;                        \
    BARRIER; STG8; VM8; WR8;                                                   \
    PRIO1; MFMA_Q(1, 0, blo); PRIO0; LGKM0;                                    \
  }

__global__ __launch_bounds__(512, 2)
void gemm_g1(const float* __restrict__ X, const bf16* __restrict__ Bt,
             bf16* __restrict__ Cstr, float* __restrict__ hm) {
    __shared__ bf16 sm[65536];                 // 128 KB
    const int tid = threadIdx.x;
    const int lane = tid & 63, w = tid >> 6;
    const int wr = w >> 2, wc = w & 3;
    const int l15 = lane & 15, l4 = lane >> 4;

    int wg = blockIdx.x;
    int swz = (wg & 7) * 64 + (wg >> 3);       // XCD-aware bijective swizzle
    const int mt = swz >> 2, ntile = swz & 3;
    const int row0 = mt * 256, col0 = ntile * 256;

    const int aoff0 = (wr * 128 + l15) * 64 + ((l4 ^ (l15 & 7)) << 3);
    const int aoff1 = aoff0 ^ 32;
    const int boff0 = (wc * 64 + l15) * 64 + ((l4 ^ (l15 & 7)) << 3);
    const int boff1 = boff0 ^ 32;

    // A staging: thread t -> row rA = t>>2 (0..127), logical chunks c0=(t&3)*2, c0+1
    const int rA = tid >> 2;
    const int c0 = (tid & 3) * 2;
    const float* gAh0 = X + (size_t)(row0 + rA) * 1024 + c0 * 8;
    const float* gAh1 = gAh0 + (size_t)128 * 1024;
    const int wA0 = rA * 64 + ((c0 ^ (rA & 7)) << 3);        // phys chunk of c0
    const int wA1 = rA * 64 + (((c0 + 1) ^ (rA & 7)) << 3);  // phys chunk of c0+1

    // B staging (gl2lds, pre-swizzled source)
    const int srow = tid >> 3;
    const int scb  = (tid & 7) ^ (srow & 7);
    const bf16* gB00 = Bt + (size_t)(col0 + srow) * 1024 + scb * 8;
    const bf16* gB01 = gB00 + 64 * 1024;
    const bf16* gB10 = gB00 + 128 * 1024;
    const bf16* gB11 = gB00 + 192 * 1024;

    f32x4 acc[8][4] = {};
    bf16x8 a[8], blo[4], bhi[4];
    f32x4 areg[8];

    // prologue: A(0)->regs; B(0)->buf0, B(1)->buf1
    ISSA(0);
    STG(gB00, gB01, 0,  32768); STG(gB10, gB11, 0,  40960);
    STG(gB00, gB01, 64, 49152); STG(gB10, gB11, 64, 57344);
    VMC(8);            // retire A(0) loads (leaves B(0)+B(1))
    WRA(0);
    VMC(4);            // retire B(0); B(1) certified at first p4's VMC(4)
    LGKM0;

#pragma unroll 1
    for (int i = 0; i < 7; ++i) {
        const int uk1 = (2 * i + 1) * 64;
        const int uk2 = (2 * i + 2) * 64;
        const int uk3 = (2 * i + 3) * 64;
        ITER_G1(uk1,
                STG(gB00, gB01, uk2, 32768), STG(gB10, gB11, uk2, 40960),
                STG(gB00, gB01, uk3, 49152), STG(gB10, gB11, uk3, 57344),
                ISSA(uk2), VMC(4), VMC(4), WRA(0));
    }
    // tail: tiles 14,15 — only A(15) (issued p1, written p4); vmcnt(0) certs
    ITER_G1(960, NOPS, NOPS, NOPS, NOPS, NOPS, VMC(0), VMC(0), NOPS);

    // epilogue: heads bf16 (stride 2048) + per-batch column sums
    const int batch = row0 >> 13;
#pragma unroll
    for (int mg = 0; mg < 8; ++mg) {
        int rbase = row0 + wr * 128 + (mg >> 2) * 64 + (mg & 3) * 16 + l4 * 4;
#pragma unroll
        for (int j = 0; j < 4; ++j) {
            size_t row = rbase + j;
#pragma unroll
            for (int ng = 0; ng < 4; ++ng) {
                int col = col0 + wc * 64 + ng * 16 + l15;
                Cstr[row * 2048 + col] = (bf16)acc[mg][ng][j];
            }
        }
    }
#pragma unroll
    for (int ng = 0; ng < 4; ++ng) {
        float s = 0;
#pragma unroll
        for (int mg = 0; mg < 8; ++mg)
#pragma unroll
            for (int j = 0; j < 4; ++j) s += acc[mg][ng][j];
        int col = col0 + wc * 64 + ng * 16 + l15;
        atomicAdd(&hm[batch * DD + col], s);
    }
}

// ---------------- GEMM2: A = merged bf16 (gl2lds), resid = x fp32 (R8 backbone) ----------------
#define ITER2(uk1, STG3, STG4, STG5, STG6, STG7, STG8, VM4, VM8)               \
  { BARRIER; STG(gA00, gA01, (uk1), 16384);                                    \
    PRIO1; READ_A2(0, 0); READ_B2(0, blo, 32768); MFMA_Q(0, 0, blo); PRIO0;    \
    BARRIER; STG(gA10, gA11, (uk1), 24576);                                    \
    PRIO1; READ_B2(1, bhi, 32768); MFMA_Q(0, 1, bhi); PRIO0;                   \
    BARRIER; STG3;                                                             \
    PRIO1; READ_A2(1, 0); MFMA_Q(1, 1, bhi); PRIO0;                            \
    BARRIER; STG4; VM4;                                                        \
    PRIO1; MFMA_Q(1, 0, blo); PRIO0;                                           \
    BARRIER; STG5;                                                             \
    PRIO1; READ_A2(0, 16384); READ_B2(0, blo, 49152); MFMA_Q(0, 0, blo); PRIO0;\
    BARRIER; STG6;                                                             \
    PRIO1; READ_B2(1, bhi, 49152); MFMA_Q(0, 1, bhi); PRIO0;                   \
    BARRIER; STG7;                                                             \
    PRIO1; READ_A2(1, 16384); MFMA_Q(1, 1, bhi); PRIO0;                        \
    BARRIER; STG8; VM8;                                                        \
    PRIO1; MFMA_Q(1, 0, blo); PRIO0;                                           \
  }

__global__ __launch_bounds__(512, 2)
void gemm_g2(const bf16* __restrict__ A, const bf16* __restrict__ Bt,
             bf16* __restrict__ Cstr, const float* __restrict__ resid,
             const float* __restrict__ bias) {
    __shared__ bf16 sm[65536];
    const int tid = threadIdx.x;
    const int lane = tid & 63, w = tid >> 6;
    const int wr = w >> 2, wc = w & 3;
    const int l15 = lane & 15, l4 = lane >> 4;

    int wg = blockIdx.x;
    int swz = (wg & 7) * 64 + (wg >> 3);
    const int mt = swz >> 2, ntile = swz & 3;
    const int row0 = mt * 256, col0 = ntile * 256;

    const int aoff0 = (wr * 128 + l15) * 64 + ((l4 ^ (l15 & 7)) << 3);
    const int aoff1 = aoff0 ^ 32;
    const int boff0 = (wc * 64 + l15) * 64 + ((l4 ^ (l15 & 7)) << 3);
    const int boff1 = boff0 ^ 32;

    const int srow = tid >> 3;
    const int scb  = (tid & 7) ^ (srow & 7);
    const int lda = 2048;
    const bf16* gA00 = A + (size_t)(row0 + srow) * lda + scb * 8;
    const bf16* gA01 = gA00 + (size_t)64 * lda;
    const bf16* gA10 = gA00 + (size_t)128 * lda;
    const bf16* gA11 = gA00 + (size_t)192 * lda;
    const bf16* gB00 = Bt + (size_t)(col0 + srow) * 1024 + scb * 8;
    const bf16* gB01 = gB00 + 64 * 1024;
    const bf16* gB10 = gB00 + 128 * 1024;
    const bf16* gB11 = gB00 + 192 * 1024;

    f32x4 acc[8][4] = {};
    bf16x8 a[8], blo[4], bhi[4];

    STG(gA00, gA01, 0,  0);     STG(gA10, gA11, 0,  8192);
    STG(gB00, gB01, 0,  32768); STG(gB10, gB11, 0,  40960);
    STG(gA00, gA01, 64, 16384); STG(gA10, gA11, 64, 24576);
    STG(gB00, gB01, 64, 49152); STG(gB10, gB11, 64, 57344);
    VMC(0);

#pragma unroll 1
    for (int i = 0; i < 7; ++i) {
        const int uk1 = (2 * i + 1) * 64;
        const int uk2 = (2 * i + 2) * 64;
        const int uk3 = (2 * i + 3) * 64;
        ITER2(uk1,
              STG(gB00, gB01, uk2, 32768), STG(gB10, gB11, uk2, 40960),
              STG(gA00, gA01, uk2, 0),     STG(gA10, gA11, uk2, 8192),
              STG(gB00, gB01, uk3, 49152), STG(gB10, gB11, uk3, 57344),
              VMC(4), VMC(4));
    }
    ITER2(960, NOPS, NOPS, NOPS, NOPS, NOPS, NOPS, VMC(0), NOPS);

    float bi[4];
#pragma unroll
    for (int ng = 0; ng < 4; ++ng) bi[ng] = bias[col0 + wc * 64 + ng * 16 + l15];
#pragma unroll
    for (int mg = 0; mg < 8; ++mg) {
        int rbase = row0 + wr * 128 + (mg >> 2) * 64 + (mg & 3) * 16 + l4 * 4;
#pragma unroll
        for (int j = 0; j < 4; ++j) {
            size_t row = rbase + j;
#pragma unroll
            for (int ng = 0; ng < 4; ++ng) {
                int col = col0 + wc * 64 + ng * 16 + l15;
                Cstr[row * 2048 + col] =
                    (bf16)(acc[mg][ng][j] + bi[ng] + resid[row * 1024 + col]);
            }
        }
    }
}

// ---- imp stage 1: pm rows (32 blocks; d-loop parallelized 8-way) ----
__global__ __launch_bounds__(256) void imp_pm(const float* __restrict__ hm,
                                              const float* __restrict__ W_pol,
                                              const float* __restrict__ b_pol,
                                              float* __restrict__ pm) {
    int bh = blockIdx.x;            // 0..31 = b*8+h
    int b = bh >> 3, h = bh & 7;
    int tid = threadIdx.x;
    int p = tid & 31, dg = tid >> 5;     // dg 0..7
    float partial = 0;
#pragma unroll
    for (int dd = 0; dd < 16; ++dd) {
        int d = dg * 16 + dd;
        partial += hm[b * DD + h * 128 + d] * (1.0f / SS)
                 * W_pol[(h * 128 + d) * 32 + p];
    }
    __shared__ float red[8][32];
    red[dg][p] = partial;
    __syncthreads();
    if (tid < 32) {
        float a = b_pol[h * 32 + p];
#pragma unroll
        for (int g = 0; g < 8; ++g) a += red[g][p];
        float pv = tanhf(a);
        float ss = pv * pv;
#pragma unroll
        for (int off = 16; off > 0; off >>= 1) ss += __shfl_xor(ss, off);
        pm[bh * 32 + p] = pv / fmaxf(sqrtf(ss), 1e-12f);
    }
}

// ---- imp stage 2: dp -> gelu -> softplus -> imp, coeff (1 block, 256 thr) ----
__global__ __launch_bounds__(256) void imp_mlp(const float* __restrict__ pm,
                                               const float* __restrict__ W_imp1,
                                               const float* __restrict__ b_imp1,
                                               const float* __restrict__ W_imp2,
                                               const float* __restrict__ b_imp2,
                                               float* __restrict__ imp_out,
                                               float* __restrict__ coeff) {
    __shared__ float pms[32][32];
    int tid = threadIdx.x;
    for (int i = tid; i < 1024; i += 256) pms[i >> 5][i & 31] = pm[i];
    __syncthreads();
    int b2 = tid >> 6, h2 = (tid >> 3) & 7, g = tid & 7;
    float dp = 0;
#pragma unroll
    for (int q = 0; q < 32; ++q) dp += pms[b2 * 8 + h2][q] * pms[b2 * 8 + g][q];
    float a2 = 0;
#pragma unroll
    for (int kk = 0; kk < 16; ++kk) {
        float zin = dp * W_imp1[kk] + b_imp1[kk];
        float zg = 0.5f * zin * (1.0f + erff(zin * 0.70710678118654752f));
        a2 += zg * W_imp2[kk];
    }
    float spin = a2 + b_imp2[0];
    float impv = (spin > 20.0f) ? spin : log1pf(expf(spin));
    if (h2 == g) impv = 0.0f;
    imp_out[tid] = impv;
    coeff[tid] = (h2 == g) ? 0.0f : 0.1f / (1.0f + impv);
}

// ---- head mixing: 16 rows/block, 16 threads/row, bf16x8 loads/stores ----
__global__ __launch_bounds__(256) void mix_k(const char* __restrict__ slots,
                                             const float* __restrict__ coeff,
                                             char* __restrict__ slots_w) {
    __shared__ float cf[64];
    int tid = threadIdx.x;
    size_t r0 = (size_t)blockIdx.x * 16;
    int b = (int)(r0 >> 13);
    if (tid < 64) cf[tid] = coeff[b * 64 + tid];
    __syncthreads();
    size_t r = r0 + (tid >> 4);
    int dd = tid & 15;
    int s = (int)(r & (SS - 1));
    float cs = (float)(s + 1) * (1.0f / SS);
    const bf16* hrow = (const bf16*)(slots + r * 4096);
    bf16* mrow = (bf16*)(slots_w + r * 4096 + 2048);
    float v[8][8];
#pragma unroll
    for (int g = 0; g < 8; ++g) {
        bf16x8 t8 = *(const bf16x8*)&hrow[g * 128 + dd * 8];
#pragma unroll
        for (int e = 0; e < 8; ++e) v[g][e] = (float)t8[e];
    }
#pragma unroll
    for (int h = 0; h < 8; ++h) {
        bf16x8 o;
#pragma unroll
        for (int e = 0; e < 8; ++e) {
            float acc = 0;
#pragma unroll
            for (int g = 0; g < 8; ++g) acc += cf[h * 8 + g] * v[g][e];
            o[e] = (bf16)(v[h][e] + cs * acc);
        }
        *(bf16x8*)&mrow[h * 128 + dd * 8] = o;
    }
}

// ---- LayerNorm: 2 rows/block, 128 thr/row, bf16x8 read + 2x float4 write ----
__global__ __launch_bounds__(256) void ln_k(char* __restrict__ slots,
                                            const float* __restrict__ gamma,
                                            const float* __restrict__ beta) {
    int tid = threadIdx.x;
    size_t r = (size_t)blockIdx.x * 2 + (tid >> 7);
    int t = tid & 127;
    const bf16* zrow = (const bf16*)(slots + r * 4096);
    float* yrow = (float*)(slots + r * 4096);
    int e0 = t * 8;
    bf16x8 zv = *(const bf16x8*)&zrow[e0];
    float v[8];
    float sum = 0, sq = 0;
#pragma unroll
    for (int e = 0; e < 8; ++e) {
        v[e] = (float)zv[e];
        sum += v[e];
        sq  += v[e] * v[e];
    }
#pragma unroll
    for (int off = 32; off > 0; off >>= 1) {
        sum += __shfl_down(sum, off);
        sq  += __shfl_down(sq, off);
    }
    __shared__ float red[4][2];
    int lane = tid & 63, wv = tid >> 6;
    if (lane == 0) { red[wv][0] = sum; red[wv][1] = sq; }
    __syncthreads();
    int rw = (tid >> 7) * 2;
    float tot = red[rw][0] + red[rw + 1][0];
    float tsq = red[rw][1] + red[rw + 1][1];
    float mu  = tot * (1.0f / DD);
    float var = tsq * (1.0f / DD) - mu * mu;
    float rs  = rsqrtf(var + 1e-5f);
    float4 g0 = *(const float4*)&gamma[e0];
    float4 g1 = *(const float4*)&gamma[e0 + 4];
    float4 b0 = *(const float4*)&beta[e0];
    float4 b1 = *(const float4*)&beta[e0 + 4];
    float4 o0, o1;
    o0.x = (v[0] - mu) * rs * g0.x + b0.x;
    o0.y = (v[1] - mu) * rs * g0.y + b0.y;
    o0.z = (v[2] - mu) * rs * g0.z + b0.z;
    o0.w = (v[3] - mu) * rs * g0.w + b0.w;
    o1.x = (v[4] - mu) * rs * g1.x + b1.x;
    o1.y = (v[5] - mu) * rs * g1.y + b1.y;
    o1.z = (v[6] - mu) * rs * g1.z + b1.z;
    o1.w = (v[7] - mu) * rs * g1.w + b1.w;
    *(float4*)&yrow[e0] = o0;
    *(float4*)&yrow[e0 + 4] = o1;
}

extern "C" void kernel_launch(void* const* d_in, const int* in_sizes, int n_in,
                              void* d_out, int out_size, void* d_ws, size_t ws_size,
                              hipStream_t stream) {
    const float* x      = (const float*)d_in[0];
    const float* W_proj = (const float*)d_in[1];
    const float* freqs  = (const float*)d_in[2];
    const float* W_pol  = (const float*)d_in[3];
    const float* b_pol  = (const float*)d_in[4];
    const float* W_imp1 = (const float*)d_in[5];
    const float* b_imp1 = (const float*)d_in[6];
    const float* W_imp2 = (const float*)d_in[7];
    const float* b_imp2 = (const float*)d_in[8];
    const float* W_out  = (const float*)d_in[9];
    const float* b_out  = (const float*)d_in[10];
    const float* gamma  = (const float*)d_in[11];
    const float* beta   = (const float*)d_in[12];

    char* ws = (char*)d_ws;
    bf16* WbT1   = (bf16*)ws;                                  // 2MB
    bf16* WoT    = (bf16*)(ws + ((size_t)2 << 20));            // 2MB
    float* hm    = (float*)(ws + ((size_t)4 << 20));           // 16KB
    float* coeff = (float*)(ws + ((size_t)4 << 20) + 16384);   // 1KB
    float* pm    = (float*)(ws + ((size_t)4 << 20) + 20480);   // 4KB

    char* slots = (char*)d_out;                      // 128MB of 4KB row slots
    float* imp_out = (float*)d_out + (size_t)MM * DD;

    prep_w<<<4096, 256, 0, stream>>>(W_proj, freqs, W_out, WbT1, WoT, hm);

    // GEMM1: A = x fp32 (fused cast); heads -> first half of row slots (+ colsums)
    gemm_g1<<<512, 512, 0, stream>>>(x, WbT1, (bf16*)slots, hm);

    imp_pm<<<32, 256, 0, stream>>>(hm, W_pol, b_pol, pm);
    imp_mlp<<<1, 256, 0, stream>>>(pm, W_imp1, b_imp1, W_imp2, b_imp2,
                                   imp_out, coeff);

    mix_k<<<MM / 16, 256, 0, stream>>>(slots, coeff, slots);   // heads -> merged

    // GEMM2: A = merged (second half, stride 2048); z -> first half; resid = x fp32
    gemm_g2<<<512, 512, 0, stream>>>((const bf16*)slots + 1024, WoT,
                                     (bf16*)slots, x, b_out);

    ln_k<<<MM / 2, 256, 0, stream>>>(slots, gamma, beta);
}

// Round 13
// 263.785 us; speedup vs baseline: 1.0490x; 1.0490x over previous
//
#include <hip/hip_runtime.h>
#include <hip/hip_bf16.h>
#include <math.h>

typedef __bf16 bf16;
typedef __bf16 bf16x2 __attribute__((ext_vector_type(2)));
typedef __bf16 bf16x4 __attribute__((ext_vector_type(4)));
typedef __bf16 bf16x8 __attribute__((ext_vector_type(8)));
typedef float  f32x4  __attribute__((ext_vector_type(4)));

#define NB 4
#define SS 8192
#define DD 1024
#define MM 32768
#define KK 1024
#define NN 1024
#define PI_F 3.14159265358979323846f

__device__ __forceinline__ void gl2lds16(const bf16* g, bf16* l) {
    __builtin_amdgcn_global_load_lds(
        (const __attribute__((address_space(1))) void*)g,
        (__attribute__((address_space(3))) void*)l, 16, 0, 0);
}

// ---- fused prep: x->bf16 cast 8/thread (blocks [0,MM/2)), W build + hm zero ----
__global__ __launch_bounds__(256) void prep_all(const float* __restrict__ x,
                                                bf16* __restrict__ xb,
                                                const float* __restrict__ W_proj,
                                                const float* __restrict__ freqs,
                                                const float* __restrict__ W_out,
                                                bf16* __restrict__ WbT1,
                                                bf16* __restrict__ WoT,
                                                float* __restrict__ hm) {
    int blk = blockIdx.x;
    if (blk < MM / 2) {
        size_t i = (size_t)blk * 2048 + threadIdx.x * 8;
        float4 v0 = *(const float4*)&x[i];
        float4 v1 = *(const float4*)&x[i + 4];
        bf16x8 o;
        o[0] = (bf16)v0.x; o[1] = (bf16)v0.y; o[2] = (bf16)v0.z; o[3] = (bf16)v0.w;
        o[4] = (bf16)v1.x; o[5] = (bf16)v1.y; o[6] = (bf16)v1.z; o[7] = (bf16)v1.w;
        *(bf16x8*)&xb[i] = o;
    } else {
        int idx = (blk - MM / 2) * 256 + threadIdx.x;   // n*1024 + k
        int n = idx >> 10, k = idx & 1023;
        int h = n >> 7, d = n & 127;
        float c = cosf(PI_F * freqs[n]);
        WbT1[idx] = (bf16)(W_proj[(size_t)h * (DD * 128) + (size_t)k * 128 + d] * c);
        WoT[idx]  = (bf16)(W_out[(size_t)k * DD + n]);
        if (idx < NB * DD) hm[idx] = 0.0f;
    }
}

// ========== 256x256x64 8-phase MFMA GEMM (R8 measured-best config, frozen) ==========
#define FENCE  asm volatile("" ::: "memory")
#define BARRIER do { FENCE; __builtin_amdgcn_s_barrier(); FENCE; } while (0)
#define PRIO1  __builtin_amdgcn_s_setprio(1)
#define PRIO0  __builtin_amdgcn_s_setprio(0)
#define VMC(N) asm volatile("s_waitcnt vmcnt(" #N ")" ::: "memory")
#define NOPS   ((void)0)

#define STG(g0, g1, uk, ldsBase)                                  \
    gl2lds16((g0) + (uk), &sm[(ldsBase) + w * 512]);              \
    gl2lds16((g1) + (uk), &sm[(ldsBase) + 4096 + w * 512]);

#define READ_A2(MQ, ab)                                                          \
    _Pragma("unroll") for (int m_ = 0; m_ < 4; ++m_) {                           \
        a[m_ * 2 + 0] = *(const bf16x8*)&sm[(ab) + aoff0 + ((MQ)*64 + m_*16)*64];\
        a[m_ * 2 + 1] = *(const bf16x8*)&sm[(ab) + aoff1 + ((MQ)*64 + m_*16)*64];\
    }
#define READ_B2(NQ, bfr, bb)                                                     \
    _Pragma("unroll") for (int n_ = 0; n_ < 2; ++n_) {                           \
        bfr[n_ * 2 + 0] = *(const bf16x8*)&sm[(bb) + boff0 + ((NQ)*32 + n_*16)*64];\
        bfr[n_ * 2 + 1] = *(const bf16x8*)&sm[(bb) + boff1 + ((NQ)*32 + n_*16)*64];\
    }

#define MFMA_Q(MQ, NQ, bfr)                                                    \
    _Pragma("unroll") for (int m_ = 0; m_ < 4; ++m_)                           \
    _Pragma("unroll") for (int n_ = 0; n_ < 2; ++n_)                           \
    _Pragma("unroll") for (int ks_ = 0; ks_ < 2; ++ks_)                        \
        acc[(MQ) * 4 + m_][(NQ) * 2 + n_] =                                    \
            __builtin_amdgcn_mfma_f32_16x16x32_bf16(                           \
                a[m_ * 2 + ks_], bfr[n_ * 2 + ks_],                            \
                acc[(MQ) * 4 + m_][(NQ) * 2 + n_], 0, 0, 0);

#define ITER(uk1, STG3, STG4, STG5, STG6, STG7, STG8, VM4, VM8)                \
  { BARRIER; STG(gA00, gA01, (uk1), 16384);                                    \
    PRIO1; READ_A2(0, 0); READ_B2(0, blo, 32768); MFMA_Q(0, 0, blo); PRIO0;    \
    BARRIER; STG(gA10, gA11, (uk1), 24576);                                    \
    PRIO1; READ_B2(1, bhi, 32768); MFMA_Q(0, 1, bhi); PRIO0;                   \
    BARRIER; STG3;                                                             \
    PRIO1; READ_A2(1, 0); MFMA_Q(1, 1, bhi); PRIO0;                            \
    BARRIER; STG4; VM4;                                                        \
    PRIO1; MFMA_Q(1, 0, blo); PRIO0;                                           \
    BARRIER; STG5;                                                             \
    PRIO1; READ_A2(0, 16384); READ_B2(0, blo, 49152); MFMA_Q(0, 0, blo); PRIO0;\
    BARRIER; STG6;                                                             \
    PRIO1; READ_B2(1, bhi, 49152); MFMA_Q(0, 1, bhi); PRIO0;                   \
    BARRIER; STG7;                                                             \
    PRIO1; READ_A2(1, 16384); MFMA_Q(1, 1, bhi); PRIO0;                        \
    BARRIER; STG8; VM8;                                                        \
    PRIO1; MFMA_Q(1, 0, blo); PRIO0;                                           \
  }

// MODE 0: C=heads bf16 (stride 2048) + fused column sums -> hm.
// MODE 1: C=z bf16 (stride 2048) = acc + bias[col] + residb[row][col].
template <int MODE>
__global__ __launch_bounds__(512, 2)
void gemm256(const bf16* __restrict__ A, int lda, const bf16* __restrict__ Bt,
             bf16* __restrict__ Cstr, const bf16* __restrict__ residb,
             const float* __restrict__ bias, float* __restrict__ hm) {
    __shared__ bf16 sm[65536];                 // 128 KB
    const int tid = threadIdx.x;
    const int lane = tid & 63, w = tid >> 6;
    const int wr = w >> 2, wc = w & 3;
    const int l15 = lane & 15, l4 = lane >> 4;

    int wg = blockIdx.x;
    int swz = (wg & 7) * 64 + (wg >> 3);       // XCD-aware bijective swizzle
    const int mt = swz >> 2, ntile = swz & 3;
    const int row0 = mt * 256, col0 = ntile * 256;

    const int aoff0 = (wr * 128 + l15) * 64 + ((l4 ^ (l15 & 7)) << 3);
    const int aoff1 = aoff0 ^ 32;
    const int boff0 = (wc * 64 + l15) * 64 + ((l4 ^ (l15 & 7)) << 3);
    const int boff1 = boff0 ^ 32;

    const int srow = tid >> 3;
    const int scb  = (tid & 7) ^ (srow & 7);
    const bf16* gA00 = A + (size_t)(row0 + srow) * lda + scb * 8;
    const bf16* gA01 = gA00 + (size_t)64 * lda;
    const bf16* gA10 = gA00 + (size_t)128 * lda;
    const bf16* gA11 = gA00 + (size_t)192 * lda;
    const bf16* gB00 = Bt + (size_t)(col0 + srow) * 1024 + scb * 8;
    const bf16* gB01 = gB00 + 64 * 1024;
    const bf16* gB10 = gB00 + 128 * 1024;
    const bf16* gB11 = gB00 + 192 * 1024;

    f32x4 acc[8][4] = {};
    bf16x8 a[8], blo[4], bhi[4];

    STG(gA00, gA01, 0,  0);     STG(gA10, gA11, 0,  8192);
    STG(gB00, gB01, 0,  32768); STG(gB10, gB11, 0,  40960);
    STG(gA00, gA01, 64, 16384); STG(gA10, gA11, 64, 24576);
    STG(gB00, gB01, 64, 49152); STG(gB10, gB11, 64, 57344);
    VMC(0);

#pragma unroll 1
    for (int i = 0; i < 7; ++i) {
        const int uk1 = (2 * i + 1) * 64;
        const int uk2 = (2 * i + 2) * 64;
        const int uk3 = (2 * i + 3) * 64;
        ITER(uk1,
             STG(gB00, gB01, uk2, 32768), STG(gB10, gB11, uk2, 40960),
             STG(gA00, gA01, uk2, 0),     STG(gA10, gA11, uk2, 8192),
             STG(gB00, gB01, uk3, 49152), STG(gB10, gB11, uk3, 57344),
             VMC(4), VMC(4));
    }
    ITER(960, NOPS, NOPS, NOPS, NOPS, NOPS, NOPS, VMC(0), NOPS);

    if (MODE == 0) {
        const int batch = row0 >> 13;
#pragma unroll
        for (int mg = 0; mg < 8; ++mg) {
            int rbase = row0 + wr * 128 + (mg >> 2) * 64 + (mg & 3) * 16 + l4 * 4;
#pragma unroll
            for (int j = 0; j < 4; ++j) {
                size_t row = rbase + j;
#pragma unroll
                for (int ng = 0; ng < 4; ++ng) {
                    int col = col0 + wc * 64 + ng * 16 + l15;
                    Cstr[row * 2048 + col] = (bf16)acc[mg][ng][j];
                }
            }
        }
#pragma unroll
        for (int ng = 0; ng < 4; ++ng) {
            float s = 0;
#pragma unroll
            for (int mg = 0; mg < 8; ++mg)
#pragma unroll
                for (int j = 0; j < 4; ++j) s += acc[mg][ng][j];
            int col = col0 + wc * 64 + ng * 16 + l15;
            atomicAdd(&hm[batch * DD + col], s);
        }
    } else {
        float bi[4];
#pragma unroll
        for (int ng = 0; ng < 4; ++ng) bi[ng] = bias[col0 + wc * 64 + ng * 16 + l15];
#pragma unroll
        for (int mg = 0; mg < 8; ++mg) {
            int rbase = row0 + wr * 128 + (mg >> 2) * 64 + (mg & 3) * 16 + l4 * 4;
#pragma unroll
            for (int j = 0; j < 4; ++j) {
                size_t row = rbase + j;
#pragma unroll
                for (int ng = 0; ng < 4; ++ng) {
                    int col = col0 + wc * 64 + ng * 16 + l15;
                    Cstr[row * 2048 + col] =
                        (bf16)(acc[mg][ng][j] + bi[ng] + (float)residb[row * 1024 + col]);
                }
            }
        }
    }
}

// ---- imp stage 1: pm rows (32 blocks; d-loop parallelized 8-way) ----
__global__ __launch_bounds__(256) void imp_pm(const float* __restrict__ hm,
                                              const float* __restrict__ W_pol,
                                              const float* __restrict__ b_pol,
                                              float* __restrict__ pm) {
    int bh = blockIdx.x;            // 0..31 = b*8+h
    int b = bh >> 3, h = bh & 7;
    int tid = threadIdx.x;
    int p = tid & 31, dg = tid >> 5;     // dg 0..7
    float partial = 0;
#pragma unroll
    for (int dd = 0; dd < 16; ++dd) {
        int d = dg * 16 + dd;
        partial += hm[b * DD + h * 128 + d] * (1.0f / SS)
                 * W_pol[(h * 128 + d) * 32 + p];
    }
    __shared__ float red[8][32];
    red[dg][p] = partial;
    __syncthreads();
    if (tid < 32) {
        float a = b_pol[h * 32 + p];
#pragma unroll
        for (int g = 0; g < 8; ++g) a += red[g][p];
        float pv = tanhf(a);
        float ss = pv * pv;
#pragma unroll
        for (int off = 16; off > 0; off >>= 1) ss += __shfl_xor(ss, off);
        pm[bh * 32 + p] = pv / fmaxf(sqrtf(ss), 1e-12f);
    }
}

// ---- imp stage 2: dp -> gelu -> softplus -> imp, coeff (1 block, 256 thr) ----
__global__ __launch_bounds__(256) void imp_mlp(const float* __restrict__ pm,
                                               const float* __restrict__ W_imp1,
                                               const float* __restrict__ b_imp1,
                                               const float* __restrict__ W_imp2,
                                               const float* __restrict__ b_imp2,
                                               float* __restrict__ imp_out,
                                               float* __restrict__ coeff) {
    __shared__ float pms[32][32];
    int tid = threadIdx.x;
    for (int i = tid; i < 1024; i += 256) pms[i >> 5][i & 31] = pm[i];
    __syncthreads();
    int b2 = tid >> 6, h2 = (tid >> 3) & 7, g = tid & 7;
    float dp = 0;
#pragma unroll
    for (int q = 0; q < 32; ++q) dp += pms[b2 * 8 + h2][q] * pms[b2 * 8 + g][q];
    float a2 = 0;
#pragma unroll
    for (int kk = 0; kk < 16; ++kk) {
        float zin = dp * W_imp1[kk] + b_imp1[kk];
        float zg = 0.5f * zin * (1.0f + erff(zin * 0.70710678118654752f));
        a2 += zg * W_imp2[kk];
    }
    float spin = a2 + b_imp2[0];
    float impv = (spin > 20.0f) ? spin : log1pf(expf(spin));
    if (h2 == g) impv = 0.0f;
    imp_out[tid] = impv;
    coeff[tid] = (h2 == g) ? 0.0f : 0.1f / (1.0f + impv);
}

// ---- head mixing: 16 rows/block, 16 threads/row, bf16x8 loads/stores ----
__global__ __launch_bounds__(256) void mix_k(const char* __restrict__ slots,
                                             const float* __restrict__ coeff,
                                             char* __restrict__ slots_w) {
    __shared__ float cf[64];
    int tid = threadIdx.x;
    size_t r0 = (size_t)blockIdx.x * 16;
    int b = (int)(r0 >> 13);
    if (tid < 64) cf[tid] = coeff[b * 64 + tid];
    __syncthreads();
    size_t r = r0 + (tid >> 4);
    int dd = tid & 15;
    int s = (int)(r & (SS - 1));
    float cs = (float)(s + 1) * (1.0f / SS);
    const bf16* hrow = (const bf16*)(slots + r * 4096);
    bf16* mrow = (bf16*)(slots_w + r * 4096 + 2048);
    float v[8][8];
#pragma unroll
    for (int g = 0; g < 8; ++g) {
        bf16x8 t8 = *(const bf16x8*)&hrow[g * 128 + dd * 8];
#pragma unroll
        for (int e = 0; e < 8; ++e) v[g][e] = (float)t8[e];
    }
#pragma unroll
    for (int h = 0; h < 8; ++h) {
        bf16x8 o;
#pragma unroll
        for (int e = 0; e < 8; ++e) {
            float acc = 0;
#pragma unroll
            for (int g = 0; g < 8; ++g) acc += cf[h * 8 + g] * v[g][e];
            o[e] = (bf16)(v[h][e] + cs * acc);
        }
        *(bf16x8*)&mrow[h * 128 + dd * 8] = o;
    }
}

// ---- LayerNorm: 2 rows/block, 128 thr/row, bf16x8 read + 2x float4 write ----
__global__ __launch_bounds__(256) void ln_k(char* __restrict__ slots,
                                            const float* __restrict__ gamma,
                                            const float* __restrict__ beta) {
    int tid = threadIdx.x;
    size_t r = (size_t)blockIdx.x * 2 + (tid >> 7);
    int t = tid & 127;
    const bf16* zrow = (const bf16*)(slots + r * 4096);
    float* yrow = (float*)(slots + r * 4096);
    int e0 = t * 8;
    bf16x8 zv = *(const bf16x8*)&zrow[e0];
    float v[8];
    float sum = 0, sq = 0;
#pragma unroll
    for (int e = 0; e < 8; ++e) {
        v[e] = (float)zv[e];
        sum += v[e];
        sq  += v[e] * v[e];
    }
#pragma unroll
    for (int off = 32; off > 0; off >>= 1) {
        sum += __shfl_down(sum, off);
        sq  += __shfl_down(sq, off);
    }
    __shared__ float red[4][2];
    int lane = tid & 63, wv = tid >> 6;
    if (lane == 0) { red[wv][0] = sum; red[wv][1] = sq; }
    __syncthreads();
    int rw = (tid >> 7) * 2;
    float tot = red[rw][0] + red[rw + 1][0];
    float tsq = red[rw][1] + red[rw + 1][1];
    float mu  = tot * (1.0f / DD);
    float var = tsq * (1.0f / DD) - mu * mu;
    float rs  = rsqrtf(var + 1e-5f);
    float4 g0 = *(const float4*)&gamma[e0];
    float4 g1 = *(const float4*)&gamma[e0 + 4];
    float4 b0 = *(const float4*)&beta[e0];
    float4 b1 = *(const float4*)&beta[e0 + 4];
    float4 o0, o1;
    o0.x = (v[0] - mu) * rs * g0.x + b0.x;
    o0.y = (v[1] - mu) * rs * g0.y + b0.y;
    o0.z = (v[2] - mu) * rs * g0.z + b0.z;
    o0.w = (v[3] - mu) * rs * g0.w + b0.w;
    o1.x = (v[4] - mu) * rs * g1.x + b1.x;
    o1.y = (v[5] - mu) * rs * g1.y + b1.y;
    o1.z = (v[6] - mu) * rs * g1.z + b1.z;
    o1.w = (v[7] - mu) * rs * g1.w + b1.w;
    *(float4*)&yrow[e0] = o0;
    *(float4*)&yrow[e0 + 4] = o1;
}

extern "C" void kernel_launch(void* const* d_in, const int* in_sizes, int n_in,
                              void* d_out, int out_size, void* d_ws, size_t ws_size,
                              hipStream_t stream) {
    const float* x      = (const float*)d_in[0];
    const float* W_proj = (const float*)d_in[1];
    const float* freqs  = (const float*)d_in[2];
    const float* W_pol  = (const float*)d_in[3];
    const float* b_pol  = (const float*)d_in[4];
    const float* W_imp1 = (const float*)d_in[5];
    const float* b_imp1 = (const float*)d_in[6];
    const float* W_imp2 = (const float*)d_in[7];
    const float* b_imp2 = (const float*)d_in[8];
    const float* W_out  = (const float*)d_in[9];
    const float* b_out  = (const float*)d_in[10];
    const float* gamma  = (const float*)d_in[11];
    const float* beta   = (const float*)d_in[12];

    char* ws = (char*)d_ws;
    bf16* xb     = (bf16*)ws;                                  // 64MB
    bf16* WbT1   = (bf16*)(ws + ((size_t)64 << 20));           // 2MB
    bf16* WoT    = (bf16*)(ws + ((size_t)66 << 20));           // 2MB
    float* hm    = (float*)(ws + ((size_t)68 << 20));          // 16KB
    float* coeff = (float*)(ws + ((size_t)68 << 20) + 16384);  // 1KB
    float* pm    = (float*)(ws + ((size_t)68 << 20) + 20480);  // 4KB

    char* slots = (char*)d_out;                      // 128MB of 4KB row slots
    float* imp_out = (float*)d_out + (size_t)MM * DD;

    prep_all<<<MM / 2 + 4096, 256, 0, stream>>>(x, xb, W_proj, freqs, W_out,
                                                WbT1, WoT, hm);

    // GEMM1: heads -> first half of row slots (+ hm column sums)
    gemm256<0><<<512, 512, 0, stream>>>(xb, 1024, WbT1, (bf16*)slots,
                                        nullptr, nullptr, hm);

    imp_pm<<<32, 256, 0, stream>>>(hm, W_pol, b_pol, pm);
    imp_mlp<<<1, 256, 0, stream>>>(pm, W_imp1, b_imp1, W_imp2, b_imp2,
                                   imp_out, coeff);

    mix_k<<<MM / 16, 256, 0, stream>>>(slots, coeff, slots);   // heads -> merged

    // GEMM2: A = merged (second half, stride 2048); z -> first half of slots
    gemm256<1><<<512, 512, 0, stream>>>((const bf16*)slots + 1024, 2048, WoT,
                                        (bf16*)slots, xb, b_out, nullptr);

    ln_k<<<MM / 2, 256, 0, stream>>>(slots, gamma, beta);
}